// Round 1
// 1255.480 us; speedup vs baseline: 1.0206x; 1.0206x over previous
//
#include <hip/hip_runtime.h>

// out[t, j] = W[j, w[t]] + b[j]   (t in [0, 32768), j in [0, 8192))
// Bucket tokens by 64-column tile of W; fused transpose+gather writes 1 KiB
// contiguous per token per block (TJ=256 rows) for DRAM-page-dense stores.

constexpr int N    = 8192;        // W is N x N
constexpr int TILE = 64;          // column-tile width (bucket granularity)
constexpr int TJ   = 256;         // row-tile height: 1 KiB contiguous per token-write
constexpr int NBKT = N / TILE;    // 128 buckets

// One block: count (LDS atomics) -> scan (Hillis-Steele) -> scatter.
__global__ __launch_bounds__(1024) void sort_k(const int* __restrict__ w, int n,
                                               int* __restrict__ offsets,
                                               int* __restrict__ sorted) {
    __shared__ int cnt[NBKT];
    __shared__ int sc[NBKT];
    __shared__ int cur[NBKT];
    const int tid = threadIdx.x;
    if (tid < NBKT) cnt[tid] = 0;
    __syncthreads();
    for (int t = tid; t < n; t += 1024) atomicAdd(&cnt[w[t] >> 6], 1);
    __syncthreads();
    if (tid < NBKT) sc[tid] = cnt[tid];
    __syncthreads();
    for (int d = 1; d < NBKT; d <<= 1) {
        int v = 0;
        if (tid < NBKT && tid >= d) v = sc[tid - d];
        __syncthreads();
        if (tid < NBKT) sc[tid] += v;
        __syncthreads();
    }
    if (tid < NBKT) {
        const int off = sc[tid] - cnt[tid];      // exclusive prefix
        cur[tid] = off;
        offsets[tid] = off;
        if (tid == NBKT - 1) offsets[NBKT] = sc[tid];
    }
    __syncthreads();
    for (int t = tid; t < n; t += 1024) {
        const int i   = w[t];
        const int pos = atomicAdd(&cur[i >> 6], 1);
        // pack token id (15b) | in-tile column (6b)
        sorted[pos] = (t << 6) | (i & 63);
    }
}

__global__ __launch_bounds__(256) void gather_k(const float* __restrict__ W,
                                                const float* __restrict__ b,
                                                const int* __restrict__ offsets,
                                                const int* __restrict__ sorted,
                                                float* __restrict__ out) {
    // XOR-swizzled tile: element (j, i) lives at dword (j<<6) | (i ^ (j & 31)).
    // -> float4 LDS writes (component-permuted) and column reads both 2-way (free).
    __shared__ alignas(16) float tile[TJ * TILE];   // exactly 64 KiB

    const int ct  = blockIdx.x;               // column tile (= bucket)
    const int rt  = blockIdx.y;               // row tile
    const int i0  = ct * TILE;
    const int j0  = rt * TJ;
    const int tid = threadIdx.x;

    // Load W[j0:j0+256, i0:i0+64] coalesced: 16 lanes x float4 per row.
    {
        const int jr = tid >> 4;              // 0..15
        const int c4 = (tid & 15) << 2;       // 0..60
        #pragma unroll
        for (int r = 0; r < TJ; r += 16) {
            const int j = r + jr;
            const float4 v = *reinterpret_cast<const float4*>(
                &W[(size_t)(j0 + j) * N + i0 + c4]);
            const int x = j & 31;
            const int p = x & 3;
            const float in[4] = {v.x, v.y, v.z, v.w};
            float4 sv;
            float* svp = reinterpret_cast<float*>(&sv);
            #pragma unroll
            for (int o = 0; o < 4; ++o) svp[o] = in[o ^ p];  // slot o <- elem (o^p)
            *reinterpret_cast<float4*>(&tile[(j << 6) + (c4 ^ (x & ~3))]) = sv;
        }
    }
    const int lane = tid & 63;
    const int wave = tid >> 6;                // 0..3
    const float bv0 = b[j0 +       lane];
    const float bv1 = b[j0 +  64 + lane];
    const float bv2 = b[j0 + 128 + lane];
    const float bv3 = b[j0 + 192 + lane];
    __syncthreads();

    const int beg   = offsets[ct];
    const int end   = offsets[ct + 1];
    const int lx    = lane & 31;
    const int lbase = lane << 6;

    // one wave per token; 4 consecutive 256B stores = 1 KiB dense per token
    int k = beg + wave;
    int v = (k < end) ? sorted[k] : 0;
    for (; k < end; k += 4) {
        const int kn = k + 4;
        const int vn = (kn < end) ? sorted[kn] : 0;   // prefetch next token word
        const int t   = v >> 6;
        const int isw = (v & 63) ^ lx;                // swizzled column, same for all s
        const float r0 = tile[lbase           + isw]; // j = lane
        const float r1 = tile[lbase +  1*4096 + isw]; // j = lane + 64
        const float r2 = tile[lbase +  2*4096 + isw]; // j = lane + 128
        const float r3 = tile[lbase +  3*4096 + isw]; // j = lane + 192
        float* o = out + (size_t)t * N + j0 + lane;
        o[0]   = r0 + bv0;
        o[64]  = r1 + bv1;
        o[128] = r2 + bv2;
        o[192] = r3 + bv3;
        v = vn;
    }
}

extern "C" void kernel_launch(void* const* d_in, const int* in_sizes, int n_in,
                              void* d_out, int out_size, void* d_ws, size_t ws_size,
                              hipStream_t stream) {
    const int*   w  = (const int*)d_in[0];      // [512*64] indices
    const float* Wm = (const float*)d_in[1];    // [8192, 8192]
    const float* b  = (const float*)d_in[2];    // [8192]
    float* out = (float*)d_out;                 // [512*64, 8192]
    const int n = in_sizes[0];                  // 32768 tokens

    int* offsets = (int*)d_ws;                  // [NBKT + 1]
    int* sorted  = offsets + NBKT + 1;          // [n]

    sort_k<<<1, 1024, 0, stream>>>(w, n, offsets, sorted);

    dim3 grid(NBKT, N / TJ);                    // 128 x 32 blocks
    gather_k<<<grid, 256, 0, stream>>>(Wm, b, offsets, sorted, out);
}